// Round 12
// baseline (317.822 us; speedup 1.0000x reference)
//
#include <hip/hip_runtime.h>
#include <hip/hip_bf16.h>
#include <stdint.h>

#define TPB 256

using f32x4 = __attribute__((ext_vector_type(4))) float;
using s16x8 = __attribute__((ext_vector_type(8))) short;
using s16x4 = __attribute__((ext_vector_type(4))) short;

__device__ __forceinline__ short f2bf(float f){
  union { float f; uint32_t u; } v; v.f = f;
  uint32_t u = v.u;
  uint32_t r = (u + 0x7fffu + ((u >> 16) & 1u)) >> 16;
  return (short)(uint16_t)r;
}
__device__ __forceinline__ float bf2f(short b){
  union { uint32_t u; float f; } v; v.u = ((uint32_t)(uint16_t)b) << 16;
  return v.f;
}
__device__ __forceinline__ f32x4 mfma16(s16x8 a, s16x8 b, f32x4 c){
  return __builtin_amdgcn_mfma_f32_16x16x32_bf16(a, b, c, 0, 0, 0);
}

#define AS1(p) ((const __attribute__((address_space(1))) void*)(p))
#define AS3(p) ((__attribute__((address_space(3))) void*)(p))

// ---------------- fused pre-GEMM prep: x cvt + W transposes (vectorized) ----------------
__device__ __forceinline__ void trans64(const float* __restrict__ W, short* __restrict__ WT,
                                        int K, int Nn, int kt, int nt,
                                        float (*ls)[68], int tid){
  const int k0 = kt*64, n0 = nt*64;
#pragma unroll
  for (int i = 0; i < 4; i++){
    const int row = i*16 + (tid >> 4);
    const int c4  = (tid & 15) * 4;
    float4 v = *(const float4*)&W[(size_t)(k0+row)*Nn + n0 + c4];
    ls[row][c4+0] = v.x; ls[row][c4+1] = v.y; ls[row][c4+2] = v.z; ls[row][c4+3] = v.w;
  }
  __syncthreads();
#pragma unroll
  for (int j = 0; j < 2; j++){
    const int nr = j*32 + (tid >> 3);
    const int kc = (tid & 7) * 8;
    s16x8 o;
#pragma unroll
    for (int e = 0; e < 8; e++) o[e] = f2bf(ls[kc+e][nr]);
    *(s16x8*)&WT[(size_t)(n0+nr)*K + k0 + kc] = o;
  }
}

__global__ void k_prep(const float* __restrict__ x, short* __restrict__ xb,
                       const float* __restrict__ Wqkv, short* __restrict__ wqkvT,
                       const float* __restrict__ Wff,  short* __restrict__ wffT){
  __shared__ float ls[64][68];
  const int tid = threadIdx.x;
  const int bid = (int)blockIdx.x;
  if (bid < 4096){
    int i = bid * TPB + tid;
    const float4* s4 = (const float4*)x;
    float4 a = s4[2*i], b = s4[2*i+1];
    s16x8 o;
    o[0]=f2bf(a.x); o[1]=f2bf(a.y); o[2]=f2bf(a.z); o[3]=f2bf(a.w);
    o[4]=f2bf(b.x); o[5]=f2bf(b.y); o[6]=f2bf(b.z); o[7]=f2bf(b.w);
    *(s16x8*)(xb + 8*(size_t)i) = o;
  } else if (bid < 7168){
    const int tb = bid - 4096;                // 3072 = 32 ktiles x 96 ntiles
    trans64(Wqkv, wqkvT, 2048, 6144, tb & 31, tb >> 5, ls, tid);
  } else {
    const int tb = bid - 7168;                // 1024 = 32 x 32
    trans64(Wff, wffT, 2048, 2048, tb & 31, tb >> 5, ls, tid);
  }
}

// ---------------- 256x128 bf16 GEMM, 3-slot LDS rotation, counted vmcnt ----------------
// FROZEN main loop (rounds 0-8); round-10 scatter epilogue restored (round-11's
// fused-RoPE epilogue was neutral: staging sync + bank conflicts cancelled the
// saved kpre round-trip). Round-12: T1 XCD chunk-swizzle — each XCD gets
// nwg/8 consecutive tiles = 6 B-panels (3 MB <= 4 MB L2) instead of touching
// all 48 (24 MB). Bijective: nwg % 8 == 0 for both launches.
template<int EPI>
__global__ void __launch_bounds__(512, 2) k_gemm8(
    const short* __restrict__ A, const short* __restrict__ Bt,
    int Nn, int K,
    const float* __restrict__ bias,
    float* __restrict__ outp,
    float* __restrict__ kvout,
    short* __restrict__ qpre, short* __restrict__ kpre, short* __restrict__ vpre)
{
  __shared__ __align__(16) short As[3][16384];
  __shared__ __align__(16) short Bs[3][8192];
  const int tid = threadIdx.x;
  const int w = tid >> 6, l = tid & 63;
  const int lrow = l & 15, lg = l >> 4;
  const int wm = w >> 1, wn = w & 1;
  // T1: XCD chunk-swizzle (HW assigns block b -> XCD b%8)
  const int nwg = (int)(gridDim.x * gridDim.y);
  const int B   = (int)blockIdx.x + (int)gridDim.x * (int)blockIdx.y;
  const int lid = (B & 7) * (nwg >> 3) + (B >> 3);
  const int m0 = (lid & 15) << 8, n0 = (lid >> 4) << 7;
  const int NT = K >> 6;

  f32x4 acc[4][4] = {};

#define STAGE_A(slot, t, j) do {                                             \
    int chunk = ((w*4 + (j)) << 6) + l;                                      \
    int row = chunk >> 3, cc = chunk & 7;                                    \
    __builtin_amdgcn_global_load_lds(                                        \
      AS1(A + (size_t)(m0+row)*K + (t)*64 + ((cc ^ (row&7)) << 3)),          \
      AS3(&As[slot][(w*4 + (j)) << 9]), 16, 0, 0);                           \
  } while(0)
#define STAGE_B(slot, t, j) do {                                             \
    int chunk = ((w*2 + (j)) << 6) + l;                                      \
    int row = chunk >> 3, cc = chunk & 7;                                    \
    __builtin_amdgcn_global_load_lds(                                        \
      AS1(Bt + (size_t)(n0+row)*K + (t)*64 + ((cc ^ (row&7)) << 3)),         \
      AS3(&Bs[slot][(w*2 + (j)) << 9]), 16, 0, 0);                           \
  } while(0)

  STAGE_A(0,0,0); STAGE_A(0,0,1); STAGE_A(0,0,2); STAGE_A(0,0,3);
  STAGE_B(0,0,0); STAGE_B(0,0,1);
  STAGE_A(1,1,0); STAGE_A(1,1,1); STAGE_A(1,1,2); STAGE_A(1,1,3);
  STAGE_B(1,1,0); STAGE_B(1,1,1);

  int slot = 0;
  for (int t = 0; t < NT; ++t){
    if (t < NT-1) asm volatile("s_waitcnt vmcnt(6)" ::: "memory");
    else          asm volatile("s_waitcnt vmcnt(0)" ::: "memory");
    __builtin_amdgcn_s_barrier();
    asm volatile("" ::: "memory");
    const int sslot = (slot == 0) ? 2 : slot - 1;
    const bool st = (t+2) < NT;
    const char* ab = (const char*)As[slot];
    const char* bb = (const char*)Bs[slot];

    s16x8 bfr[4][2];
#pragma unroll
    for (int ni = 0; ni < 4; ni++){
      int row = wn*64 + ni*16 + lrow;
#pragma unroll
      for (int ks = 0; ks < 2; ks++)
        bfr[ni][ks] = *(const s16x8*)(bb + row*128 + ((ks*64 + lg*16) ^ ((row&7)<<4)));
    }
    s16x8 af[2][2];
#pragma unroll
    for (int mi = 0; mi < 2; mi++){
      int row = wm*64 + mi*16 + lrow;
#pragma unroll
      for (int ks = 0; ks < 2; ks++)
        af[mi][ks] = *(const s16x8*)(ab + row*128 + ((ks*64 + lg*16) ^ ((row&7)<<4)));
    }
    if (st){ STAGE_A(sslot,t+2,0); STAGE_A(sslot,t+2,1); STAGE_B(sslot,t+2,0); }
    __builtin_amdgcn_s_setprio(1);
#pragma unroll
    for (int ks = 0; ks < 2; ks++)
#pragma unroll
      for (int mi = 0; mi < 2; mi++)
#pragma unroll
        for (int ni = 0; ni < 4; ni++)
          acc[mi][ni] = mfma16(af[mi][ks], bfr[ni][ks], acc[mi][ni]);
    __builtin_amdgcn_s_setprio(0);

    s16x8 af2[2][2];
#pragma unroll
    for (int mi = 0; mi < 2; mi++){
      int row = wm*64 + (mi+2)*16 + lrow;
#pragma unroll
      for (int ks = 0; ks < 2; ks++)
        af2[mi][ks] = *(const s16x8*)(ab + row*128 + ((ks*64 + lg*16) ^ ((row&7)<<4)));
    }
    if (st){ STAGE_A(sslot,t+2,2); STAGE_A(sslot,t+2,3); STAGE_B(sslot,t+2,1); }
    __builtin_amdgcn_s_setprio(1);
#pragma unroll
    for (int ks = 0; ks < 2; ks++)
#pragma unroll
      for (int mi = 0; mi < 2; mi++)
#pragma unroll
        for (int ni = 0; ni < 4; ni++)
          acc[mi+2][ni] = mfma16(af2[mi][ks], bfr[ni][ks], acc[mi+2][ni]);
    __builtin_amdgcn_s_setprio(0);
    slot = (slot == 2) ? 0 : slot + 1;
  }
#undef STAGE_A
#undef STAGE_B

#pragma unroll
  for (int mi = 0; mi < 4; mi++){
#pragma unroll
    for (int ni = 0; ni < 4; ni++){
      const int c  = n0 + wn*64 + ni*16 + lrow;
      const int mb = m0 + wm*64 + mi*16 + lg*4;
      const float bv = bias[c];
      if (EPI == 1){
#pragma unroll
        for (int r = 0; r < 4; r++)
          outp[(size_t)(mb+r)*Nn + c] = acc[mi][ni][r] + bv;
      } else {
        const int s = c >> 11, h = (c >> 7) & 15, tt = c & 127;
#pragma unroll
        for (int r = 0; r < 4; r++){
          const int m = mb + r;
          const int b = m >> 11, n = m & 2047;
          const int bh = b*16 + h;
          const float val = acc[mi][ni][r] + bv;
          if (s == 0){
            qpre[((size_t)bh*2048 + n)*128 + tt] = f2bf(val);
          } else if (s == 1){
            kvout[((size_t)bh*2560 + 512 + n)*128 + tt] = val;
            kpre[((size_t)bh*2048 + n)*128 + tt] = f2bf(val);
          } else {
            kvout[(size_t)(32 + bh)*327680 + (size_t)(512 + n)*128 + tt] = val;
            vpre[((size_t)bh*2048 + n)*128 + tt] = f2bf(val);
          }
        }
      }
    }
  }
}

// ---------------- fused K/V prep ----------------
// blocks [0,2048): rope-K new | [2048,4096): V^T new | [4096,4608): rope-K prefix+copy
// | [4608,5120): V^T prefix+copy.  V^T stores vectorized to 8 B (s16x4):
// 4 iters x {4 ds_reads (bank (p+t)%32, worst 2-way = free) + 1 store} vs
// 16 scalar 2 B stores (G13).
__global__ void k_pre(const short* __restrict__ kpre, short* __restrict__ kr,
                      const short* __restrict__ vpre, short* __restrict__ vT,
                      const float* __restrict__ pk, float* __restrict__ kvout0,
                      const float* __restrict__ pv, float* __restrict__ kvout1){
  __shared__ float ls[32][129];
  const int tid = threadIdx.x;
  const int bid = (int)blockIdx.x;
  if (bid < 2048){
    int gid = bid * TPB + tid;
    int jb = (gid & 7) * 8; size_t row = gid >> 3;
    int bh = (int)(row >> 11), n = (int)(row & 2047);
    int pos = 512 + n;
    s16x8 v1 = *(const s16x8*)&kpre[row*128 + jb];
    s16x8 v2 = *(const s16x8*)&kpre[row*128 + 64 + jb];
    s16x8 o1, o2;
#pragma unroll
    for (int e = 0; e < 8; e++){
      float invf = __expf((float)(jb + e) * (-9.210340371976184f/64.0f));
      float sn, cs; __sincosf((float)pos * invf, &sn, &cs);
      float x1 = bf2f(v1[e]), x2 = bf2f(v2[e]);
      o1[e] = f2bf(x1*cs - x2*sn);
      o2[e] = f2bf(x2*cs + x1*sn);
    }
    size_t drow = (size_t)bh*2560 + pos;
    *(s16x8*)&kr[drow*128 + jb]      = o1;
    *(s16x8*)&kr[drow*128 + 64 + jb] = o2;
  } else if (bid < 4096){
    int t2 = bid - 2048;
    int bh = t2 >> 6, nt = t2 & 63;
    int n0 = nt*32;
#pragma unroll
    for (int i = 0; i < 16; i++){
      int idx = i*TPB + tid; int p = idx >> 7, t = idx & 127;
      ls[p][t] = bf2f(vpre[((size_t)bh*2048 + n0 + p)*128 + t]);
    }
    __syncthreads();
#pragma unroll
    for (int i = 0; i < 4; i++){
      int idx = i*TPB + tid; int t = idx >> 3, pq = (idx & 7) * 4;
      s16x4 o;
#pragma unroll
      for (int e = 0; e < 4; e++) o[e] = f2bf(ls[pq+e][t]);
      *(s16x4*)&vT[((size_t)bh*128 + t)*2560 + 512 + n0 + pq] = o;
    }
  } else if (bid < 4608){
    int gid = (bid - 4096) * TPB + tid;
    int jb = (gid & 7) * 8; size_t row = gid >> 3;
    int bh = (int)(row >> 9), p = (int)(row & 511);
    float4 a1 = *(const float4*)&pk[row*128 + jb];
    float4 a2 = *(const float4*)&pk[row*128 + jb + 4];
    float4 b1 = *(const float4*)&pk[row*128 + 64 + jb];
    float4 b2 = *(const float4*)&pk[row*128 + 64 + jb + 4];
    size_t orow = (size_t)bh*2560 + p;
    *(float4*)&kvout0[orow*128 + jb]          = a1;
    *(float4*)&kvout0[orow*128 + jb + 4]      = a2;
    *(float4*)&kvout0[orow*128 + 64 + jb]     = b1;
    *(float4*)&kvout0[orow*128 + 64 + jb + 4] = b2;
    float x1[8] = {a1.x,a1.y,a1.z,a1.w,a2.x,a2.y,a2.z,a2.w};
    float x2[8] = {b1.x,b1.y,b1.z,b1.w,b2.x,b2.y,b2.z,b2.w};
    s16x8 o1, o2;
#pragma unroll
    for (int e = 0; e < 8; e++){
      float invf = __expf((float)(jb + e) * (-9.210340371976184f/64.0f));
      float sn, cs; __sincosf((float)p * invf, &sn, &cs);
      o1[e] = f2bf(x1[e]*cs - x2[e]*sn);
      o2[e] = f2bf(x2[e]*cs + x1[e]*sn);
    }
    *(s16x8*)&kr[orow*128 + jb]      = o1;
    *(s16x8*)&kr[orow*128 + 64 + jb] = o2;
  } else {
    int t2 = bid - 4608;
    int bh = t2 >> 4, pt = t2 & 15;
    int p0 = pt*32;
#pragma unroll
    for (int i = 0; i < 16; i++){
      int idx = i*TPB + tid; int p = idx >> 7, t = idx & 127;
      float v = pv[((size_t)bh*512 + p0 + p)*128 + t];
      ls[p][t] = v;
      kvout1[((size_t)bh*2560 + p0 + p)*128 + t] = v;
    }
    __syncthreads();
#pragma unroll
    for (int i = 0; i < 4; i++){
      int idx = i*TPB + tid; int t = idx >> 3, pq = (idx & 7) * 4;
      s16x4 o;
#pragma unroll
      for (int e = 0; e < 4; e++) o[e] = f2bf(ls[pq+e][t]);
      *(s16x4*)&vT[((size_t)bh*128 + t)*2560 + p0 + pq] = o;
    }
  }
}

// ---------------- flash attention: QBLK=32/wave, fused RoPE-Q, exp2 softmax ----------------
// (round-9 form, unchanged)
__global__ void __launch_bounds__(256, 2) k_attn(
    const short* __restrict__ qr, const short* __restrict__ kr,
    const short* __restrict__ vT, short* __restrict__ attno)
{
  __shared__ short Ks[2][64*128];      // 32768 B (reused as epilogue staging)
  __shared__ short VTs[2][128*64];     // 32768 B
  __shared__ short Ps[4][32*64];       // 16384 B  -> total 81920 B
  const int bh = blockIdx.x;
  const int qt = 15 - (int)blockIdx.y;         // long blocks dispatch first
  const int n = 10 + 2*qt;                     // K/V tiles of 64 keys
  const int tid = threadIdx.x, w = tid >> 6, l = tid & 63;
  const int lrow = l & 15, lg = l >> 4;
  const int b = bh >> 4, h = bh & 15;
  const int qbw = qt*128 + w*32;

  s16x8 qf[2][4];
  {
    const float sc = 0.088388347648318447f * 1.4426950408889634f; // /sqrt(128) * log2e
#pragma unroll
    for (int qb = 0; qb < 2; qb++){
      const int nr = qbw + qb*16 + lrow;
      const size_t rr = (size_t)bh*2048 + nr;
#pragma unroll
      for (int ks = 0; ks < 4; ks++)
        qf[qb][ks] = *(const s16x8*)&qr[rr*128 + ks*32 + lg*8];
#pragma unroll
      for (int ks = 0; ks < 2; ks++){
#pragma unroll
        for (int e = 0; e < 8; e++){
          const int j = ks*32 + lg*8 + e;
          const float invf = __expf((float)j * (-9.210340371976184f/64.0f));
          float sn, cs;
          __sincosf((float)nr * invf, &sn, &cs);
          float x1 = bf2f(qf[qb][ks][e]), x2 = bf2f(qf[qb][ks+2][e]);
          qf[qb][ks][e]   = f2bf((x1*cs - x2*sn) * sc);
          qf[qb][ks+2][e] = f2bf((x2*cs + x1*sn) * sc);
        }
      }
    }
  }

#define STAGE_KV(buf, kv0s) do {                                                    \
    _Pragma("unroll")                                                               \
    for (int i_ = 0; i_ < 4; i_++){                                                 \
      int chunk = i_*256 + tid;                                                     \
      int row = chunk >> 4, cc = (chunk & 15) ^ (row & 7);                          \
      __builtin_amdgcn_global_load_lds(                                             \
        AS1(kr + ((size_t)bh*2560 + (kv0s) + row)*128 + cc*8),                      \
        AS3((char*)Ks[buf] + (i_*256 + w*64)*16), 16, 0, 0);                        \
    }                                                                               \
    _Pragma("unroll")                                                               \
    for (int i_ = 0; i_ < 4; i_++){                                                 \
      int chunk = i_*256 + tid;                                                     \
      int row = chunk >> 3, cc = (chunk & 7) ^ (row & 7);                           \
      __builtin_amdgcn_global_load_lds(                                             \
        AS1(vT + ((size_t)bh*128 + row)*2560 + (kv0s) + cc*8),                      \
        AS3((char*)VTs[buf] + (i_*256 + w*64)*16), 16, 0, 0);                       \
    }                                                                               \
  } while(0)

  STAGE_KV(0, 0);
  STAGE_KV(1, 64);

  char* psw = (char*)&Ps[w][0];
  f32x4 acc0[8] = {}, acc1[8] = {};
  float mr0 = -1e30f, ls0 = 0.f;
  float mr1 = -1e30f, ls1 = 0.f;

  for (int t = 0; t < n; t++){
    if (t+1 < n) asm volatile("s_waitcnt vmcnt(8)" ::: "memory");
    else         asm volatile("s_waitcnt vmcnt(0)" ::: "memory");
    __builtin_amdgcn_s_barrier();
    asm volatile("" ::: "memory");
    const char* kb_ = (const char*)Ks[t&1];
    const char* vb_ = (const char*)VTs[t&1];
    const int kv0 = t*64;

    f32x4 sf0[4], sf1[4];
    __builtin_amdgcn_s_setprio(1);
#pragma unroll
    for (int kb = 0; kb < 4; kb++){
      f32x4 s0 = {0.f,0.f,0.f,0.f}, s1 = {0.f,0.f,0.f,0.f};
#pragma unroll
      for (int ks = 0; ks < 4; ks++){
        int row  = kb*16 + lrow;
        int colb = ks*64 + lg*16;
        s16x8 kf = *(const s16x8*)(kb_ + row*256 + (colb ^ ((row&7)<<4)));
        s0 = mfma16(kf, qf[0][ks], s0);
        s1 = mfma16(kf, qf[1][ks], s1);
      }
      sf0[kb] = s0; sf1[kb] = s1;
    }
    __builtin_amdgcn_s_setprio(0);

    if (kv0 + 63 > 512 + qbw){
      const int qme0 = 512 + qbw + lrow;
      const int qme1 = qme0 + 16;
#pragma unroll
      for (int kb = 0; kb < 4; kb++)
#pragma unroll
        for (int r = 0; r < 4; r++){
          int kg = kv0 + kb*16 + lg*4 + r;
          if (kg > qme0) sf0[kb][r] = -1e30f;
          if (kg > qme1) sf1[kb][r] = -1e30f;
        }
    }

    {
      float m_ = fmaxf(
          fmaxf(fmaxf(fmaxf(sf0[0][0],sf0[0][1]),fmaxf(sf0[0][2],sf0[0][3])),
                fmaxf(fmaxf(sf0[1][0],sf0[1][1]),fmaxf(sf0[1][2],sf0[1][3]))),
          fmaxf(fmaxf(fmaxf(sf0[2][0],sf0[2][1]),fmaxf(sf0[2][2],sf0[2][3])),
                fmaxf(fmaxf(sf0[3][0],sf0[3][1]),fmaxf(sf0[3][2],sf0[3][3]))));
      m_ = fmaxf(m_, __shfl_xor(m_, 16));
      m_ = fmaxf(m_, __shfl_xor(m_, 32));
      if (__any(m_ > mr0 + 11.5f)){
        float mnew = fmaxf(mr0, m_);
        float sc = __builtin_amdgcn_exp2f(mr0 - mnew);
        mr0 = mnew; ls0 *= sc;
        float scr[4];
#pragma unroll
        for (int r = 0; r < 4; r++)
          scr[r] = __shfl(sc, (l & 48) | (lg*4 + r));
#pragma unroll
        for (int dt = 0; dt < 8; dt++)
#pragma unroll
          for (int r = 0; r < 4; r++) acc0[dt][r] *= scr[r];
      }
#pragma unroll
      for (int kb = 0; kb < 4; kb++){
        float p0 = __builtin_amdgcn_exp2f(sf0[kb][0] - mr0);
        float p1 = __builtin_amdgcn_exp2f(sf0[kb][1] - mr0);
        float p2 = __builtin_amdgcn_exp2f(sf0[kb][2] - mr0);
        float p3 = __builtin_amdgcn_exp2f(sf0[kb][3] - mr0);
        ls0 += (p0+p1)+(p2+p3);
        s16x4 pk4 = { f2bf(p0), f2bf(p1), f2bf(p2), f2bf(p3) };
        *(s16x4*)(psw + (lrow*128 + ((kb*32 + lg*8) ^ ((lrow&7)<<4)))) = pk4;
      }
    }
    {
      float m_ = fmaxf(
          fmaxf(fmaxf(fmaxf(sf1[0][0],sf1[0][1]),fmaxf(sf1[0][2],sf1[0][3])),
                fmaxf(fmaxf(sf1[1][0],sf1[1][1]),fmaxf(sf1[1][2],sf1[1][3]))),
          fmaxf(fmaxf(fmaxf(sf1[2][0],sf1[2][1]),fmaxf(sf1[2][2],sf1[2][3])),
                fmaxf(fmaxf(sf1[3][0],sf1[3][1]),fmaxf(sf1[3][2],sf1[3][3]))));
      m_ = fmaxf(m_, __shfl_xor(m_, 16));
      m_ = fmaxf(m_, __shfl_xor(m_, 32));
      if (__any(m_ > mr1 + 11.5f)){
        float mnew = fmaxf(mr1, m_);
        float sc = __builtin_amdgcn_exp2f(mr1 - mnew);
        mr1 = mnew; ls1 *= sc;
        float scr[4];
#pragma unroll
        for (int r = 0; r < 4; r++)
          scr[r] = __shfl(sc, (l & 48) | (lg*4 + r));
#pragma unroll
        for (int dt = 0; dt < 8; dt++)
#pragma unroll
          for (int r = 0; r < 4; r++) acc1[dt][r] *= scr[r];
      }
#pragma unroll
      for (int kb = 0; kb < 4; kb++){
        float p0 = __builtin_amdgcn_exp2f(sf1[kb][0] - mr1);
        float p1 = __builtin_amdgcn_exp2f(sf1[kb][1] - mr1);
        float p2 = __builtin_amdgcn_exp2f(sf1[kb][2] - mr1);
        float p3 = __builtin_amdgcn_exp2f(sf1[kb][3] - mr1);
        ls1 += (p0+p1)+(p2+p3);
        s16x4 pk4 = { f2bf(p0), f2bf(p1), f2bf(p2), f2bf(p3) };
        *(s16x4*)(psw + ((16 + lrow)*128 + ((kb*32 + lg*8) ^ ((lrow&7)<<4)))) = pk4;
      }
    }

    __builtin_amdgcn_s_setprio(1);
#pragma unroll
    for (int kp = 0; kp < 2; kp++){
      s16x8 pa0 = *(const s16x8*)(psw + (lrow*128       + ((kp*64 + lg*16) ^ ((lrow&7)<<4))));
      s16x8 pa1 = *(const s16x8*)(psw + ((16+lrow)*128  + ((kp*64 + lg*16) ^ ((lrow&7)<<4))));
#pragma unroll
      for (int dt = 0; dt < 8; dt++){
        int vrow = dt*16 + lrow;
        int vcolb = kp*64 + lg*16;
        s16x8 vf = *(const s16x8*)(vb_ + vrow*128 + (vcolb ^ ((vrow&7)<<4)));
        acc0[dt] = mfma16(pa0, vf, acc0[dt]);
        acc1[dt] = mfma16(pa1, vf, acc1[dt]);
      }
    }
    __builtin_amdgcn_s_setprio(0);

    asm volatile("" ::: "memory");
    __builtin_amdgcn_s_barrier();
    asm volatile("" ::: "memory");
    if (t + 2 < n) STAGE_KV(t&1, (t+2)*64);
  }

  // ---- epilogue: normalize, stage to LDS (Ks is dead), coalesced store
  float lsa = ls0;
  lsa += __shfl_xor(lsa, 16);
  lsa += __shfl_xor(lsa, 32);
  float lsb = ls1;
  lsb += __shfl_xor(lsb, 16);
  lsb += __shfl_xor(lsb, 32);
  float linv0[4], linv1[4];
#pragma unroll
  for (int r = 0; r < 4; r++){
    linv0[r] = 1.f / __shfl(lsa, (l & 48) | (lg*4 + r));
    linv1[r] = 1.f / __shfl(lsb, (l & 48) | (lg*4 + r));
  }
  short* lout = (short*)Ks;   // 128 rows x 128 cols bf16 = 32768 B
#pragma unroll
  for (int dt = 0; dt < 8; dt++){
#pragma unroll
    for (int r = 0; r < 4; r++){
      const int col = dt*16 + lrow;
      lout[(w*32 + lg*4 + r)*128 + col]      = f2bf(acc0[dt][r] * linv0[r]);
      lout[(w*32 + 16 + lg*4 + r)*128 + col] = f2bf(acc1[dt][r] * linv1[r]);
    }
  }
  __syncthreads();
  const size_t gbase = ((size_t)b*2048 + qt*128)*2048 + (size_t)h*128;
#pragma unroll
  for (int i = 0; i < 8; i++){
    const int row = (tid >> 4) + i*16;
    const int chunk = tid & 15;
    s16x8 v = *(const s16x8*)&lout[row*128 + chunk*8];
    *(s16x8*)&attno[gbase + (size_t)row*2048 + chunk*8] = v;
  }
#undef STAGE_KV
}

// ---------------- launch ----------------
extern "C" void kernel_launch(void* const* d_in, const int* in_sizes, int n_in,
                              void* d_out, int out_size, void* d_ws, size_t ws_size,
                              hipStream_t stream)
{
  const float* x    = (const float*)d_in[0];
  const float* pk   = (const float*)d_in[2];
  const float* pv   = (const float*)d_in[3];
  const float* Wqkv = (const float*)d_in[4];
  const float* bqkv = (const float*)d_in[5];
  const float* Wff  = (const float*)d_in[6];
  const float* bff  = (const float*)d_in[7];
  float* out   = (float*)d_out;
  float* kvout = out + 8388608;

  char* ws = (char*)d_ws;
  short* xb    = (short*)(ws);
  short* wqkvT = (short*)(ws + 16777216);
  short* wffT  = (short*)(ws + 41943040);
  short* qpre  = (short*)(ws + 50331648);
  short* kpre  = (short*)(ws + 67108864);
  short* vpre  = (short*)(ws + 83886080);
  short* krp   = (short*)(ws + 117440512);
  short* vTp   = (short*)(ws + 138412032);
  short* attno = (short*)(ws + 159383552);

  k_prep<<<8192, TPB, 0, stream>>>(x, xb, Wqkv, wqkvT, Wff, wffT);

  k_gemm8<0><<<dim3(16, 48), 512, 0, stream>>>(xb, wqkvT, 6144, 2048, bqkv,
                                               nullptr, kvout, qpre, kpre, vpre);

  k_pre<<<5120, TPB, 0, stream>>>(kpre, krp, vpre, vTp,
                                  pk, kvout, pv, kvout + (size_t)32*327680);

  k_attn<<<dim3(32, 16), 256, 0, stream>>>(qpre, krp, vTp, attno);

  k_gemm8<1><<<dim3(16, 16), 512, 0, stream>>>(attno, wffT, 2048, 2048, bff,
                                               out, nullptr, nullptr, nullptr, nullptr);
}

// Round 13
// 296.451 us; speedup vs baseline: 1.0721x; 1.0721x over previous
//
#include <hip/hip_runtime.h>
#include <hip/hip_bf16.h>
#include <stdint.h>

#define TPB 256

using f32x4 = __attribute__((ext_vector_type(4))) float;
using s16x8 = __attribute__((ext_vector_type(8))) short;
using s16x4 = __attribute__((ext_vector_type(4))) short;

__device__ __forceinline__ short f2bf(float f){
  union { float f; uint32_t u; } v; v.f = f;
  uint32_t u = v.u;
  uint32_t r = (u + 0x7fffu + ((u >> 16) & 1u)) >> 16;
  return (short)(uint16_t)r;
}
__device__ __forceinline__ float bf2f(short b){
  union { uint32_t u; float f; } v; v.u = ((uint32_t)(uint16_t)b) << 16;
  return v.f;
}
__device__ __forceinline__ f32x4 mfma16(s16x8 a, s16x8 b, f32x4 c){
  return __builtin_amdgcn_mfma_f32_16x16x32_bf16(a, b, c, 0, 0, 0);
}

#define AS1(p) ((const __attribute__((address_space(1))) void*)(p))
#define AS3(p) ((__attribute__((address_space(3))) void*)(p))

// ---------------- fused pre-GEMM prep: x cvt + W transposes (vectorized) ----------------
__device__ __forceinline__ void trans64(const float* __restrict__ W, short* __restrict__ WT,
                                        int K, int Nn, int kt, int nt,
                                        float (*ls)[68], int tid){
  const int k0 = kt*64, n0 = nt*64;
#pragma unroll
  for (int i = 0; i < 4; i++){
    const int row = i*16 + (tid >> 4);
    const int c4  = (tid & 15) * 4;
    float4 v = *(const float4*)&W[(size_t)(k0+row)*Nn + n0 + c4];
    ls[row][c4+0] = v.x; ls[row][c4+1] = v.y; ls[row][c4+2] = v.z; ls[row][c4+3] = v.w;
  }
  __syncthreads();
#pragma unroll
  for (int j = 0; j < 2; j++){
    const int nr = j*32 + (tid >> 3);
    const int kc = (tid & 7) * 8;
    s16x8 o;
#pragma unroll
    for (int e = 0; e < 8; e++) o[e] = f2bf(ls[kc+e][nr]);
    *(s16x8*)&WT[(size_t)(n0+nr)*K + k0 + kc] = o;
  }
}

__global__ void k_prep(const float* __restrict__ x, short* __restrict__ xb,
                       const float* __restrict__ Wqkv, short* __restrict__ wqkvT,
                       const float* __restrict__ Wff,  short* __restrict__ wffT){
  __shared__ float ls[64][68];
  const int tid = threadIdx.x;
  const int bid = (int)blockIdx.x;
  if (bid < 4096){
    int i = bid * TPB + tid;
    const float4* s4 = (const float4*)x;
    float4 a = s4[2*i], b = s4[2*i+1];
    s16x8 o;
    o[0]=f2bf(a.x); o[1]=f2bf(a.y); o[2]=f2bf(a.z); o[3]=f2bf(a.w);
    o[4]=f2bf(b.x); o[5]=f2bf(b.y); o[6]=f2bf(b.z); o[7]=f2bf(b.w);
    *(s16x8*)(xb + 8*(size_t)i) = o;
  } else if (bid < 7168){
    const int tb = bid - 4096;                // 3072 = 32 ktiles x 96 ntiles
    trans64(Wqkv, wqkvT, 2048, 6144, tb & 31, tb >> 5, ls, tid);
  } else {
    const int tb = bid - 7168;                // 1024 = 32 x 32
    trans64(Wff, wffT, 2048, 2048, tb & 31, tb >> 5, ls, tid);
  }
}

// ---------------- 256x128 bf16 GEMM, 3-slot LDS rotation, counted vmcnt ----------------
// FROZEN main loop (rounds 0-8); round-10 block mapping RESTORED.
// Round-12 lesson (FETCH 123->209 MB): the default bx-major mapping is already
// XCD-optimal — XCD = B%8 = bx%8 gives each XCD 2 M-tiles (2 MB of A,
// L2-resident) with B streaming through L3. Chunk-swizzling to N-panel chunks
// put 16 MB of A on each XCD's 4 MB L2 -> thrash, +70% fetch, +17 us.
// Do NOT XCD-swizzle this grid.
template<int EPI>
__global__ void __launch_bounds__(512, 2) k_gemm8(
    const short* __restrict__ A, const short* __restrict__ Bt,
    int Nn, int K,
    const float* __restrict__ bias,
    float* __restrict__ outp,
    float* __restrict__ kvout,
    short* __restrict__ qpre, short* __restrict__ kpre, short* __restrict__ vpre)
{
  __shared__ __align__(16) short As[3][16384];
  __shared__ __align__(16) short Bs[3][8192];
  const int tid = threadIdx.x;
  const int w = tid >> 6, l = tid & 63;
  const int lrow = l & 15, lg = l >> 4;
  const int wm = w >> 1, wn = w & 1;
  const int m0 = blockIdx.x << 8, n0 = blockIdx.y << 7;
  const int NT = K >> 6;

  f32x4 acc[4][4] = {};

#define STAGE_A(slot, t, j) do {                                             \
    int chunk = ((w*4 + (j)) << 6) + l;                                      \
    int row = chunk >> 3, cc = chunk & 7;                                    \
    __builtin_amdgcn_global_load_lds(                                        \
      AS1(A + (size_t)(m0+row)*K + (t)*64 + ((cc ^ (row&7)) << 3)),          \
      AS3(&As[slot][(w*4 + (j)) << 9]), 16, 0, 0);                           \
  } while(0)
#define STAGE_B(slot, t, j) do {                                             \
    int chunk = ((w*2 + (j)) << 6) + l;                                      \
    int row = chunk >> 3, cc = chunk & 7;                                    \
    __builtin_amdgcn_global_load_lds(                                        \
      AS1(Bt + (size_t)(n0+row)*K + (t)*64 + ((cc ^ (row&7)) << 3)),         \
      AS3(&Bs[slot][(w*2 + (j)) << 9]), 16, 0, 0);                           \
  } while(0)

  STAGE_A(0,0,0); STAGE_A(0,0,1); STAGE_A(0,0,2); STAGE_A(0,0,3);
  STAGE_B(0,0,0); STAGE_B(0,0,1);
  STAGE_A(1,1,0); STAGE_A(1,1,1); STAGE_A(1,1,2); STAGE_A(1,1,3);
  STAGE_B(1,1,0); STAGE_B(1,1,1);

  int slot = 0;
  for (int t = 0; t < NT; ++t){
    if (t < NT-1) asm volatile("s_waitcnt vmcnt(6)" ::: "memory");
    else          asm volatile("s_waitcnt vmcnt(0)" ::: "memory");
    __builtin_amdgcn_s_barrier();
    asm volatile("" ::: "memory");
    const int sslot = (slot == 0) ? 2 : slot - 1;
    const bool st = (t+2) < NT;
    const char* ab = (const char*)As[slot];
    const char* bb = (const char*)Bs[slot];

    s16x8 bfr[4][2];
#pragma unroll
    for (int ni = 0; ni < 4; ni++){
      int row = wn*64 + ni*16 + lrow;
#pragma unroll
      for (int ks = 0; ks < 2; ks++)
        bfr[ni][ks] = *(const s16x8*)(bb + row*128 + ((ks*64 + lg*16) ^ ((row&7)<<4)));
    }
    s16x8 af[2][2];
#pragma unroll
    for (int mi = 0; mi < 2; mi++){
      int row = wm*64 + mi*16 + lrow;
#pragma unroll
      for (int ks = 0; ks < 2; ks++)
        af[mi][ks] = *(const s16x8*)(ab + row*128 + ((ks*64 + lg*16) ^ ((row&7)<<4)));
    }
    if (st){ STAGE_A(sslot,t+2,0); STAGE_A(sslot,t+2,1); STAGE_B(sslot,t+2,0); }
    __builtin_amdgcn_s_setprio(1);
#pragma unroll
    for (int ks = 0; ks < 2; ks++)
#pragma unroll
      for (int mi = 0; mi < 2; mi++)
#pragma unroll
        for (int ni = 0; ni < 4; ni++)
          acc[mi][ni] = mfma16(af[mi][ks], bfr[ni][ks], acc[mi][ni]);
    __builtin_amdgcn_s_setprio(0);

    s16x8 af2[2][2];
#pragma unroll
    for (int mi = 0; mi < 2; mi++){
      int row = wm*64 + (mi+2)*16 + lrow;
#pragma unroll
      for (int ks = 0; ks < 2; ks++)
        af2[mi][ks] = *(const s16x8*)(ab + row*128 + ((ks*64 + lg*16) ^ ((row&7)<<4)));
    }
    if (st){ STAGE_A(sslot,t+2,2); STAGE_A(sslot,t+2,3); STAGE_B(sslot,t+2,1); }
    __builtin_amdgcn_s_setprio(1);
#pragma unroll
    for (int ks = 0; ks < 2; ks++)
#pragma unroll
      for (int mi = 0; mi < 2; mi++)
#pragma unroll
        for (int ni = 0; ni < 4; ni++)
          acc[mi+2][ni] = mfma16(af2[mi][ks], bfr[ni][ks], acc[mi+2][ni]);
    __builtin_amdgcn_s_setprio(0);
    slot = (slot == 2) ? 0 : slot + 1;
  }
#undef STAGE_A
#undef STAGE_B

#pragma unroll
  for (int mi = 0; mi < 4; mi++){
#pragma unroll
    for (int ni = 0; ni < 4; ni++){
      const int c  = n0 + wn*64 + ni*16 + lrow;
      const int mb = m0 + wm*64 + mi*16 + lg*4;
      const float bv = bias[c];
      if (EPI == 1){
#pragma unroll
        for (int r = 0; r < 4; r++)
          outp[(size_t)(mb+r)*Nn + c] = acc[mi][ni][r] + bv;
      } else {
        const int s = c >> 11, h = (c >> 7) & 15, tt = c & 127;
#pragma unroll
        for (int r = 0; r < 4; r++){
          const int m = mb + r;
          const int b = m >> 11, n = m & 2047;
          const int bh = b*16 + h;
          const float val = acc[mi][ni][r] + bv;
          if (s == 0){
            qpre[((size_t)bh*2048 + n)*128 + tt] = f2bf(val);
          } else if (s == 1){
            kvout[((size_t)bh*2560 + 512 + n)*128 + tt] = val;
            kpre[((size_t)bh*2048 + n)*128 + tt] = f2bf(val);
          } else {
            kvout[(size_t)(32 + bh)*327680 + (size_t)(512 + n)*128 + tt] = val;
            vpre[((size_t)bh*2048 + n)*128 + tt] = f2bf(val);
          }
        }
      }
    }
  }
}

// ---------------- fused K/V prep ----------------
// blocks [0,2048): rope-K new | [2048,4096): V^T new | [4096,4608): rope-K prefix+copy
// | [4608,5120): V^T prefix+copy.  V^T stores vectorized to 8 B (s16x4):
// 4 iters x {4 ds_reads (bank (p+t)%32, worst 2-way = free) + 1 store} vs
// 16 scalar 2 B stores (G13).
__global__ void k_pre(const short* __restrict__ kpre, short* __restrict__ kr,
                      const short* __restrict__ vpre, short* __restrict__ vT,
                      const float* __restrict__ pk, float* __restrict__ kvout0,
                      const float* __restrict__ pv, float* __restrict__ kvout1){
  __shared__ float ls[32][129];
  const int tid = threadIdx.x;
  const int bid = (int)blockIdx.x;
  if (bid < 2048){
    int gid = bid * TPB + tid;
    int jb = (gid & 7) * 8; size_t row = gid >> 3;
    int bh = (int)(row >> 11), n = (int)(row & 2047);
    int pos = 512 + n;
    s16x8 v1 = *(const s16x8*)&kpre[row*128 + jb];
    s16x8 v2 = *(const s16x8*)&kpre[row*128 + 64 + jb];
    s16x8 o1, o2;
#pragma unroll
    for (int e = 0; e < 8; e++){
      float invf = __expf((float)(jb + e) * (-9.210340371976184f/64.0f));
      float sn, cs; __sincosf((float)pos * invf, &sn, &cs);
      float x1 = bf2f(v1[e]), x2 = bf2f(v2[e]);
      o1[e] = f2bf(x1*cs - x2*sn);
      o2[e] = f2bf(x2*cs + x1*sn);
    }
    size_t drow = (size_t)bh*2560 + pos;
    *(s16x8*)&kr[drow*128 + jb]      = o1;
    *(s16x8*)&kr[drow*128 + 64 + jb] = o2;
  } else if (bid < 4096){
    int t2 = bid - 2048;
    int bh = t2 >> 6, nt = t2 & 63;
    int n0 = nt*32;
#pragma unroll
    for (int i = 0; i < 16; i++){
      int idx = i*TPB + tid; int p = idx >> 7, t = idx & 127;
      ls[p][t] = bf2f(vpre[((size_t)bh*2048 + n0 + p)*128 + t]);
    }
    __syncthreads();
#pragma unroll
    for (int i = 0; i < 4; i++){
      int idx = i*TPB + tid; int t = idx >> 3, pq = (idx & 7) * 4;
      s16x4 o;
#pragma unroll
      for (int e = 0; e < 4; e++) o[e] = f2bf(ls[pq+e][t]);
      *(s16x4*)&vT[((size_t)bh*128 + t)*2560 + 512 + n0 + pq] = o;
    }
  } else if (bid < 4608){
    int gid = (bid - 4096) * TPB + tid;
    int jb = (gid & 7) * 8; size_t row = gid >> 3;
    int bh = (int)(row >> 9), p = (int)(row & 511);
    float4 a1 = *(const float4*)&pk[row*128 + jb];
    float4 a2 = *(const float4*)&pk[row*128 + jb + 4];
    float4 b1 = *(const float4*)&pk[row*128 + 64 + jb];
    float4 b2 = *(const float4*)&pk[row*128 + 64 + jb + 4];
    size_t orow = (size_t)bh*2560 + p;
    *(float4*)&kvout0[orow*128 + jb]          = a1;
    *(float4*)&kvout0[orow*128 + jb + 4]      = a2;
    *(float4*)&kvout0[orow*128 + 64 + jb]     = b1;
    *(float4*)&kvout0[orow*128 + 64 + jb + 4] = b2;
    float x1[8] = {a1.x,a1.y,a1.z,a1.w,a2.x,a2.y,a2.z,a2.w};
    float x2[8] = {b1.x,b1.y,b1.z,b1.w,b2.x,b2.y,b2.z,b2.w};
    s16x8 o1, o2;
#pragma unroll
    for (int e = 0; e < 8; e++){
      float invf = __expf((float)(jb + e) * (-9.210340371976184f/64.0f));
      float sn, cs; __sincosf((float)p * invf, &sn, &cs);
      o1[e] = f2bf(x1[e]*cs - x2[e]*sn);
      o2[e] = f2bf(x2[e]*cs + x1[e]*sn);
    }
    *(s16x8*)&kr[orow*128 + jb]      = o1;
    *(s16x8*)&kr[orow*128 + 64 + jb] = o2;
  } else {
    int t2 = bid - 4608;
    int bh = t2 >> 4, pt = t2 & 15;
    int p0 = pt*32;
#pragma unroll
    for (int i = 0; i < 16; i++){
      int idx = i*TPB + tid; int p = idx >> 7, t = idx & 127;
      float v = pv[((size_t)bh*512 + p0 + p)*128 + t];
      ls[p][t] = v;
      kvout1[((size_t)bh*2560 + p0 + p)*128 + t] = v;
    }
    __syncthreads();
#pragma unroll
    for (int i = 0; i < 4; i++){
      int idx = i*TPB + tid; int t = idx >> 3, pq = (idx & 7) * 4;
      s16x4 o;
#pragma unroll
      for (int e = 0; e < 4; e++) o[e] = f2bf(ls[pq+e][t]);
      *(s16x4*)&vT[((size_t)bh*128 + t)*2560 + p0 + pq] = o;
    }
  }
}

// ---------------- flash attention: QBLK=32/wave, fused RoPE-Q, exp2 softmax ----------------
// (round-9 form, unchanged)
__global__ void __launch_bounds__(256, 2) k_attn(
    const short* __restrict__ qr, const short* __restrict__ kr,
    const short* __restrict__ vT, short* __restrict__ attno)
{
  __shared__ short Ks[2][64*128];      // 32768 B (reused as epilogue staging)
  __shared__ short VTs[2][128*64];     // 32768 B
  __shared__ short Ps[4][32*64];       // 16384 B  -> total 81920 B
  const int bh = blockIdx.x;
  const int qt = 15 - (int)blockIdx.y;         // long blocks dispatch first
  const int n = 10 + 2*qt;                     // K/V tiles of 64 keys
  const int tid = threadIdx.x, w = tid >> 6, l = tid & 63;
  const int lrow = l & 15, lg = l >> 4;
  const int b = bh >> 4, h = bh & 15;
  const int qbw = qt*128 + w*32;

  s16x8 qf[2][4];
  {
    const float sc = 0.088388347648318447f * 1.4426950408889634f; // /sqrt(128) * log2e
#pragma unroll
    for (int qb = 0; qb < 2; qb++){
      const int nr = qbw + qb*16 + lrow;
      const size_t rr = (size_t)bh*2048 + nr;
#pragma unroll
      for (int ks = 0; ks < 4; ks++)
        qf[qb][ks] = *(const s16x8*)&qr[rr*128 + ks*32 + lg*8];
#pragma unroll
      for (int ks = 0; ks < 2; ks++){
#pragma unroll
        for (int e = 0; e < 8; e++){
          const int j = ks*32 + lg*8 + e;
          const float invf = __expf((float)j * (-9.210340371976184f/64.0f));
          float sn, cs;
          __sincosf((float)nr * invf, &sn, &cs);
          float x1 = bf2f(qf[qb][ks][e]), x2 = bf2f(qf[qb][ks+2][e]);
          qf[qb][ks][e]   = f2bf((x1*cs - x2*sn) * sc);
          qf[qb][ks+2][e] = f2bf((x2*cs + x1*sn) * sc);
        }
      }
    }
  }

#define STAGE_KV(buf, kv0s) do {                                                    \
    _Pragma("unroll")                                                               \
    for (int i_ = 0; i_ < 4; i_++){                                                 \
      int chunk = i_*256 + tid;                                                     \
      int row = chunk >> 4, cc = (chunk & 15) ^ (row & 7);                          \
      __builtin_amdgcn_global_load_lds(                                             \
        AS1(kr + ((size_t)bh*2560 + (kv0s) + row)*128 + cc*8),                      \
        AS3((char*)Ks[buf] + (i_*256 + w*64)*16), 16, 0, 0);                        \
    }                                                                               \
    _Pragma("unroll")                                                               \
    for (int i_ = 0; i_ < 4; i_++){                                                 \
      int chunk = i_*256 + tid;                                                     \
      int row = chunk >> 3, cc = (chunk & 7) ^ (row & 7);                           \
      __builtin_amdgcn_global_load_lds(                                             \
        AS1(vT + ((size_t)bh*128 + row)*2560 + (kv0s) + cc*8),                      \
        AS3((char*)VTs[buf] + (i_*256 + w*64)*16), 16, 0, 0);                       \
    }                                                                               \
  } while(0)

  STAGE_KV(0, 0);
  STAGE_KV(1, 64);

  char* psw = (char*)&Ps[w][0];
  f32x4 acc0[8] = {}, acc1[8] = {};
  float mr0 = -1e30f, ls0 = 0.f;
  float mr1 = -1e30f, ls1 = 0.f;

  for (int t = 0; t < n; t++){
    if (t+1 < n) asm volatile("s_waitcnt vmcnt(8)" ::: "memory");
    else         asm volatile("s_waitcnt vmcnt(0)" ::: "memory");
    __builtin_amdgcn_s_barrier();
    asm volatile("" ::: "memory");
    const char* kb_ = (const char*)Ks[t&1];
    const char* vb_ = (const char*)VTs[t&1];
    const int kv0 = t*64;

    f32x4 sf0[4], sf1[4];
    __builtin_amdgcn_s_setprio(1);
#pragma unroll
    for (int kb = 0; kb < 4; kb++){
      f32x4 s0 = {0.f,0.f,0.f,0.f}, s1 = {0.f,0.f,0.f,0.f};
#pragma unroll
      for (int ks = 0; ks < 4; ks++){
        int row  = kb*16 + lrow;
        int colb = ks*64 + lg*16;
        s16x8 kf = *(const s16x8*)(kb_ + row*256 + (colb ^ ((row&7)<<4)));
        s0 = mfma16(kf, qf[0][ks], s0);
        s1 = mfma16(kf, qf[1][ks], s1);
      }
      sf0[kb] = s0; sf1[kb] = s1;
    }
    __builtin_amdgcn_s_setprio(0);

    if (kv0 + 63 > 512 + qbw){
      const int qme0 = 512 + qbw + lrow;
      const int qme1 = qme0 + 16;
#pragma unroll
      for (int kb = 0; kb < 4; kb++)
#pragma unroll
        for (int r = 0; r < 4; r++){
          int kg = kv0 + kb*16 + lg*4 + r;
          if (kg > qme0) sf0[kb][r] = -1e30f;
          if (kg > qme1) sf1[kb][r] = -1e30f;
        }
    }

    {
      float m_ = fmaxf(
          fmaxf(fmaxf(fmaxf(sf0[0][0],sf0[0][1]),fmaxf(sf0[0][2],sf0[0][3])),
                fmaxf(fmaxf(sf0[1][0],sf0[1][1]),fmaxf(sf0[1][2],sf0[1][3]))),
          fmaxf(fmaxf(fmaxf(sf0[2][0],sf0[2][1]),fmaxf(sf0[2][2],sf0[2][3])),
                fmaxf(fmaxf(sf0[3][0],sf0[3][1]),fmaxf(sf0[3][2],sf0[3][3]))));
      m_ = fmaxf(m_, __shfl_xor(m_, 16));
      m_ = fmaxf(m_, __shfl_xor(m_, 32));
      if (__any(m_ > mr0 + 11.5f)){
        float mnew = fmaxf(mr0, m_);
        float sc = __builtin_amdgcn_exp2f(mr0 - mnew);
        mr0 = mnew; ls0 *= sc;
        float scr[4];
#pragma unroll
        for (int r = 0; r < 4; r++)
          scr[r] = __shfl(sc, (l & 48) | (lg*4 + r));
#pragma unroll
        for (int dt = 0; dt < 8; dt++)
#pragma unroll
          for (int r = 0; r < 4; r++) acc0[dt][r] *= scr[r];
      }
#pragma unroll
      for (int kb = 0; kb < 4; kb++){
        float p0 = __builtin_amdgcn_exp2f(sf0[kb][0] - mr0);
        float p1 = __builtin_amdgcn_exp2f(sf0[kb][1] - mr0);
        float p2 = __builtin_amdgcn_exp2f(sf0[kb][2] - mr0);
        float p3 = __builtin_amdgcn_exp2f(sf0[kb][3] - mr0);
        ls0 += (p0+p1)+(p2+p3);
        s16x4 pk4 = { f2bf(p0), f2bf(p1), f2bf(p2), f2bf(p3) };
        *(s16x4*)(psw + (lrow*128 + ((kb*32 + lg*8) ^ ((lrow&7)<<4)))) = pk4;
      }
    }
    {
      float m_ = fmaxf(
          fmaxf(fmaxf(fmaxf(sf1[0][0],sf1[0][1]),fmaxf(sf1[0][2],sf1[0][3])),
                fmaxf(fmaxf(sf1[1][0],sf1[1][1]),fmaxf(sf1[1][2],sf1[1][3]))),
          fmaxf(fmaxf(fmaxf(sf1[2][0],sf1[2][1]),fmaxf(sf1[2][2],sf1[2][3])),
                fmaxf(fmaxf(sf1[3][0],sf1[3][1]),fmaxf(sf1[3][2],sf1[3][3]))));
      m_ = fmaxf(m_, __shfl_xor(m_, 16));
      m_ = fmaxf(m_, __shfl_xor(m_, 32));
      if (__any(m_ > mr1 + 11.5f)){
        float mnew = fmaxf(mr1, m_);
        float sc = __builtin_amdgcn_exp2f(mr1 - mnew);
        mr1 = mnew; ls1 *= sc;
        float scr[4];
#pragma unroll
        for (int r = 0; r < 4; r++)
          scr[r] = __shfl(sc, (l & 48) | (lg*4 + r));
#pragma unroll
        for (int dt = 0; dt < 8; dt++)
#pragma unroll
          for (int r = 0; r < 4; r++) acc1[dt][r] *= scr[r];
      }
#pragma unroll
      for (int kb = 0; kb < 4; kb++){
        float p0 = __builtin_amdgcn_exp2f(sf1[kb][0] - mr1);
        float p1 = __builtin_amdgcn_exp2f(sf1[kb][1] - mr1);
        float p2 = __builtin_amdgcn_exp2f(sf1[kb][2] - mr1);
        float p3 = __builtin_amdgcn_exp2f(sf1[kb][3] - mr1);
        ls1 += (p0+p1)+(p2+p3);
        s16x4 pk4 = { f2bf(p0), f2bf(p1), f2bf(p2), f2bf(p3) };
        *(s16x4*)(psw + ((16 + lrow)*128 + ((kb*32 + lg*8) ^ ((lrow&7)<<4)))) = pk4;
      }
    }

    __builtin_amdgcn_s_setprio(1);
#pragma unroll
    for (int kp = 0; kp < 2; kp++){
      s16x8 pa0 = *(const s16x8*)(psw + (lrow*128       + ((kp*64 + lg*16) ^ ((lrow&7)<<4))));
      s16x8 pa1 = *(const s16x8*)(psw + ((16+lrow)*128  + ((kp*64 + lg*16) ^ ((lrow&7)<<4))));
#pragma unroll
      for (int dt = 0; dt < 8; dt++){
        int vrow = dt*16 + lrow;
        int vcolb = kp*64 + lg*16;
        s16x8 vf = *(const s16x8*)(vb_ + vrow*128 + (vcolb ^ ((vrow&7)<<4)));
        acc0[dt] = mfma16(pa0, vf, acc0[dt]);
        acc1[dt] = mfma16(pa1, vf, acc1[dt]);
      }
    }
    __builtin_amdgcn_s_setprio(0);

    asm volatile("" ::: "memory");
    __builtin_amdgcn_s_barrier();
    asm volatile("" ::: "memory");
    if (t + 2 < n) STAGE_KV(t&1, (t+2)*64);
  }

  // ---- epilogue: normalize, stage to LDS (Ks is dead), coalesced store
  float lsa = ls0;
  lsa += __shfl_xor(lsa, 16);
  lsa += __shfl_xor(lsa, 32);
  float lsb = ls1;
  lsb += __shfl_xor(lsb, 16);
  lsb += __shfl_xor(lsb, 32);
  float linv0[4], linv1[4];
#pragma unroll
  for (int r = 0; r < 4; r++){
    linv0[r] = 1.f / __shfl(lsa, (l & 48) | (lg*4 + r));
    linv1[r] = 1.f / __shfl(lsb, (l & 48) | (lg*4 + r));
  }
  short* lout = (short*)Ks;   // 128 rows x 128 cols bf16 = 32768 B
#pragma unroll
  for (int dt = 0; dt < 8; dt++){
#pragma unroll
    for (int r = 0; r < 4; r++){
      const int col = dt*16 + lrow;
      lout[(w*32 + lg*4 + r)*128 + col]      = f2bf(acc0[dt][r] * linv0[r]);
      lout[(w*32 + 16 + lg*4 + r)*128 + col] = f2bf(acc1[dt][r] * linv1[r]);
    }
  }
  __syncthreads();
  const size_t gbase = ((size_t)b*2048 + qt*128)*2048 + (size_t)h*128;
#pragma unroll
  for (int i = 0; i < 8; i++){
    const int row = (tid >> 4) + i*16;
    const int chunk = tid & 15;
    s16x8 v = *(const s16x8*)&lout[row*128 + chunk*8];
    *(s16x8*)&attno[gbase + (size_t)row*2048 + chunk*8] = v;
  }
#undef STAGE_KV
}

// ---------------- launch ----------------
extern "C" void kernel_launch(void* const* d_in, const int* in_sizes, int n_in,
                              void* d_out, int out_size, void* d_ws, size_t ws_size,
                              hipStream_t stream)
{
  const float* x    = (const float*)d_in[0];
  const float* pk   = (const float*)d_in[2];
  const float* pv   = (const float*)d_in[3];
  const float* Wqkv = (const float*)d_in[4];
  const float* bqkv = (const float*)d_in[5];
  const float* Wff  = (const float*)d_in[6];
  const float* bff  = (const float*)d_in[7];
  float* out   = (float*)d_out;
  float* kvout = out + 8388608;

  char* ws = (char*)d_ws;
  short* xb    = (short*)(ws);
  short* wqkvT = (short*)(ws + 16777216);
  short* wffT  = (short*)(ws + 41943040);
  short* qpre  = (short*)(ws + 50331648);
  short* kpre  = (short*)(ws + 67108864);
  short* vpre  = (short*)(ws + 83886080);
  short* krp   = (short*)(ws + 117440512);
  short* vTp   = (short*)(ws + 138412032);
  short* attno = (short*)(ws + 159383552);

  k_prep<<<8192, TPB, 0, stream>>>(x, xb, Wqkv, wqkvT, Wff, wffT);

  k_gemm8<0><<<dim3(16, 48), 512, 0, stream>>>(xb, wqkvT, 6144, 2048, bqkv,
                                               nullptr, kvout, qpre, kpre, vpre);

  k_pre<<<5120, TPB, 0, stream>>>(kpre, krp, vpre, vTp,
                                  pk, kvout, pv, kvout + (size_t)32*327680);

  k_attn<<<dim3(32, 16), 256, 0, stream>>>(qpre, krp, vTp, attno);

  k_gemm8<1><<<dim3(16, 16), 512, 0, stream>>>(attno, wffT, 2048, 2048, bff,
                                               out, nullptr, nullptr, nullptr, nullptr);
}